// Round 7
// baseline (675.353 us; speedup 1.0000x reference)
//
#include <hip/hip_runtime.h>
#include <math.h>

#define NROWS 8192
#define DIM   512
#define NCLS  10
#define GT    4        // 128-wide tile grid (4x4)
#define GPAIR 10       // lower-triangle 128-tile pairs
#define NMAT  32

__device__ __forceinline__ float rdlane(float v, int l) {
    return __int_as_float(__builtin_amdgcn_readlane(__float_as_int(v), l));
}

// ---------------------------------------------------------------- counts/lists
__global__ __launch_bounds__(256) void k_count(const int* __restrict__ label,
                                               int* __restrict__ counts,
                                               int* __restrict__ lists) {
    __shared__ int hist[NCLS];
    __shared__ int base[NCLS];
    __shared__ int lofs[NCLS];
    int tid = threadIdx.x;
    int i = blockIdx.x * 256 + tid;
    if (tid < NCLS) { hist[tid] = 0; lofs[tid] = 0; }
    __syncthreads();
    int c = label[i];
    atomicAdd(&hist[c], 1);
    __syncthreads();
    if (tid < NCLS) base[tid] = atomicAdd(&counts[tid], hist[tid]);
    __syncthreads();
    int lpos = atomicAdd(&lofs[c], 1);
    lists[(size_t)c * NROWS + base[c] + lpos] = i;
}

// ---------------------------------------------------------------- per-class Grams
// G packed: [tensor(2)][class(10)][pair(10)][128*128]; lower pairs ti>=tj over 4x4.
__global__ __launch_bounds__(512) void k_gram(const float* __restrict__ Z,
                                              const float* __restrict__ Zb,
                                              const int* __restrict__ counts,
                                              const int* __restrict__ lists,
                                              float* __restrict__ G) {
    int pt = blockIdx.x;
    int c  = blockIdx.y;
    int tz = blockIdx.z;
    int ti = 0, tj = 0;
    { int p = pt;
      for (int r = 0; r < GT; ++r) { if (p <= r) { ti = r; tj = p; break; } p -= (r + 1); } }
    bool diag = (ti == tj);

    const float* __restrict__ src = tz ? Zb : Z;
    float* __restrict__ Gout = G + (((size_t)tz * NCLS + c) * GPAIR + pt) * 16384;
    int cnt = counts[c];
    const int* __restrict__ list = lists + (size_t)c * NROWS;

    __shared__ float As[2][16][132];
    __shared__ float Bs[2][16][132];
    int tid = threadIdx.x;
    int gid = tid >> 8;          // k-group
    int t   = tid & 255;
    int tx = t & 15, ty = t >> 4;
    int srow = t >> 4, sc4 = t & 15;

    float acc[8][8];
    #pragma unroll
    for (int r = 0; r < 8; ++r)
        #pragma unroll
        for (int s = 0; s < 8; ++s) acc[r][s] = 0.f;

    for (int base0 = 0; base0 < cnt; base0 += 32) {
        int gr = base0 + gid * 16 + srow;
        float4 va0 = make_float4(0.f, 0.f, 0.f, 0.f), va1 = va0, vb0 = va0, vb1 = va0;
        if (gr < cnt) {
            int ridx = list[gr];
            const float* __restrict__ rp = src + (size_t)ridx * DIM;
            va0 = *(const float4*)&rp[ti * 128 + sc4 * 4];
            va1 = *(const float4*)&rp[ti * 128 + 64 + sc4 * 4];
            if (!diag) {
                vb0 = *(const float4*)&rp[tj * 128 + sc4 * 4];
                vb1 = *(const float4*)&rp[tj * 128 + 64 + sc4 * 4];
            }
        }
        *(float4*)&As[gid][srow][sc4 * 4]      = va0;
        *(float4*)&As[gid][srow][64 + sc4 * 4] = va1;
        if (!diag) {
            *(float4*)&Bs[gid][srow][sc4 * 4]      = vb0;
            *(float4*)&Bs[gid][srow][64 + sc4 * 4] = vb1;
        }
        __syncthreads();

        const float (*__restrict__ Ap)[132] = As[gid];
        const float (*__restrict__ Bp)[132] = diag ? As[gid] : Bs[gid];
        #pragma unroll
        for (int kk = 0; kk < 16; ++kk) {
            float a[8], b[8];
            *(float4*)&a[0] = *(const float4*)&Ap[kk][ty * 4];
            *(float4*)&a[4] = *(const float4*)&Ap[kk][64 + ty * 4];
            *(float4*)&b[0] = *(const float4*)&Bp[kk][tx * 4];
            *(float4*)&b[4] = *(const float4*)&Bp[kk][64 + tx * 4];
            #pragma unroll
            for (int r = 0; r < 8; ++r)
                #pragma unroll
                for (int s = 0; s < 8; ++s)
                    acc[r][s] += a[r] * b[s];
        }
        __syncthreads();
    }

    // reduce group1 into group0 through LDS. Fully unrolled (rule #20: runtime
    // index into acc[][] spills the whole accumulator — R4's 6x regression).
    float* red = (float*)&As[0][0][0];
    #pragma unroll
    for (int r = 0; r < 8; ++r) {
        __syncthreads();
        if (gid == 1) {
            #pragma unroll
            for (int s = 0; s < 8; ++s) red[t * 8 + s] = acc[r][s];
        }
        __syncthreads();
        if (gid == 0) {
            #pragma unroll
            for (int s = 0; s < 8; ++s) acc[r][s] += red[t * 8 + s];
        }
    }
    if (gid == 0) {
        #pragma unroll
        for (int r = 0; r < 8; ++r) {
            int row = (r < 4) ? (ty * 4 + r) : (64 + ty * 4 + r - 4);
            float4 v0 = make_float4(acc[r][0], acc[r][1], acc[r][2], acc[r][3]);
            float4 v1 = make_float4(acc[r][4], acc[r][5], acc[r][6], acc[r][7]);
            *(float4*)&Gout[(size_t)row * 128 + tx * 4]      = v0;
            *(float4*)&Gout[(size_t)row * 128 + 64 + tx * 4] = v1;
        }
    }
}

// ---------------------------------------------------------------- assemble (lower tiles only)
__global__ __launch_bounds__(256) void k_assemble(const float* __restrict__ G,
                                                  const int* __restrict__ counts,
                                                  float* __restrict__ A) {
    int pt = blockIdx.x;
    int m  = blockIdx.y;
    int ti = 0, tj = 0;
    { int p = pt;
      for (int r = 0; r < GT; ++r) { if (p <= r) { ti = r; tj = p; break; } p -= (r + 1); } }

    const size_t TILE = 16384;
    const float* __restrict__ Gz  = G;
    const float* __restrict__ Gzb = G + (size_t)NCLS * GPAIR * TILE;
    float* __restrict__ Am = A + (size_t)m * DIM * DIM;
    int tid = threadIdx.x;

    int mode; int c; float sc;
    if (m < 10)      { mode = 0; c = m;      sc = 1024.f / ((float)counts[c] + 1e-8f); }
    else if (m < 20) { mode = 1; c = m - 10; sc = 1024.f / ((float)counts[c] + 1e-8f); }
    else if (m < 30) { mode = 2; c = m - 20; sc = 512.f / (float)counts[c]; }
    else             { mode = (m == 30) ? 3 : 4; c = 0; sc = 0.125f; }

    #pragma unroll 1
    for (int h = 0; h < 16; ++h) {
        int id = h * 256 + tid;
        int row = id >> 5, c4 = id & 31;
        size_t off = (size_t)row * 128 + c4 * 4;
        float4 g = make_float4(0.f, 0.f, 0.f, 0.f);
        if (mode == 0) {
            g = *(const float4*)&Gz[((size_t)c * GPAIR + pt) * TILE + off];
        } else if (mode == 1) {
            g = *(const float4*)&Gzb[((size_t)c * GPAIR + pt) * TILE + off];
        } else if (mode == 2) {
            float4 a = *(const float4*)&Gz [((size_t)c * GPAIR + pt) * TILE + off];
            float4 b = *(const float4*)&Gzb[((size_t)c * GPAIR + pt) * TILE + off];
            g.x = a.x + b.x; g.y = a.y + b.y; g.z = a.z + b.z; g.w = a.w + b.w;
        } else if (mode == 3) {
            for (int cc = 0; cc < NCLS; ++cc) {
                float4 t = *(const float4*)&Gz[((size_t)cc * GPAIR + pt) * TILE + off];
                g.x += t.x; g.y += t.y; g.z += t.z; g.w += t.w;
            }
        } else {
            for (int cc = 0; cc < NCLS; ++cc) {
                float4 t = *(const float4*)&Gzb[((size_t)cc * GPAIR + pt) * TILE + off];
                g.x += t.x; g.y += t.y; g.z += t.z; g.w += t.w;
            }
        }
        g.x *= sc; g.y *= sc; g.z *= sc; g.w *= sc;
        if (ti == tj) {
            int cb = c4 * 4;
            if (row == cb)     g.x += 1.f;
            if (row == cb + 1) g.y += 1.f;
            if (row == cb + 2) g.z += 1.f;
            if (row == cb + 3) g.w += 1.f;
        }
        *(float4*)&Am[(size_t)(ti * 128 + row) * DIM + tj * 128 + c4 * 4] = g;
    }
}

// ---------------------------------------------------------------- full Cholesky, ONE launch
// One block (512 thr) per matrix. Per panel p: load diag -> fact (wave 0, readlane)
// -> trsm (448 rows, row/thread, float4 Dl reads) -> syrk (tiles over 8 waves).
// T lives in LDS (Tl[64][448]); no global T, no inter-launch drains.
__global__ __launch_bounds__(512) void k_chol(float* __restrict__ A,
                                              float* __restrict__ ld) {
    int m = blockIdx.x;
    float* __restrict__ Am = A + (size_t)m * DIM * DIM;
    int tid = threadIdx.x;
    int wave = tid >> 6, lane6 = tid & 63;

    __shared__ float Dl[64][68];     // 17.0 KB (stride 68: float4-aligned rows)
    __shared__ float dinv[64];
    __shared__ float Tl[64][448];    // 114.7 KB: Tl[k][r] = T[r][k]

    #pragma unroll 1
    for (int p = 0; p < 8; ++p) {
        int col0 = p * 64, col1 = col0 + 64;
        int mt = DIM - col1;          // trailing rows
        int K = mt >> 6;

        // load diag tile (64 rows x 16 float4)
        for (int h = tid; h < 1024; h += 512) {
            int r = h >> 4, c4 = h & 15;
            *(float4*)&Dl[r][c4 * 4] = *(const float4*)&Am[(size_t)(col0 + r) * DIM + col0 + c4 * 4];
        }
        __syncthreads();

        // fact by wave 0: row-per-lane, readlane broadcasts (SALU, no LDS pipe)
        if (tid < 64) {
            int lane = tid;
            float row_[64];
            #pragma unroll
            for (int j = 0; j < 64; ++j) row_[j] = Dl[lane][j];
            float dval = 1.f;
            #pragma unroll
            for (int k = 0; k < 64; ++k) {
                float piv = rdlane(row_[k], k);
                float s = 1.0f / sqrtf(piv);
                float lik = row_[k] * s;
                dval = (lane == k) ? lik : dval;
                row_[k] = lik;
                #pragma unroll
                for (int j = k + 1; j < 64; ++j)
                    row_[j] -= lik * rdlane(lik, j);
            }
            #pragma unroll
            for (int j = 0; j < 64; ++j) Dl[lane][j] = row_[j];
            dinv[lane] = 1.f / dval;
            float v = 2.f * logf(dval);
            #pragma unroll
            for (int off = 32; off > 0; off >>= 1) v += __shfl_down(v, off);
            if (lane == 0) atomicAdd(&ld[m], v);
        }
        __syncthreads();

        // trsm: thread r solves row (col1+r): t = B_row * L_d^{-T}; Tl[i][r] = t[i]
        if (tid < mt) {
            const float* __restrict__ Brow = Am + (size_t)(col1 + tid) * DIM + col0;
            float t[64];
            float4 bv;
            #pragma unroll
            for (int i = 0; i < 64; ++i) {
                if ((i & 3) == 0) bv = *(const float4*)&Brow[i];
                float a0 = (i & 3) == 0 ? bv.x : ((i & 3) == 1 ? bv.y : ((i & 3) == 2 ? bv.z : bv.w));
                float a1 = 0.f, a2 = 0.f, a3 = 0.f;
                int mm = 0;
                #pragma unroll
                for (; mm + 3 < i; mm += 4) {
                    float4 d = *(const float4*)&Dl[i][mm];
                    a0 -= t[mm]     * d.x;
                    a1 -= t[mm + 1] * d.y;
                    a2 -= t[mm + 2] * d.z;
                    a3 -= t[mm + 3] * d.w;
                }
                #pragma unroll
                for (; mm < i; ++mm) a0 -= t[mm] * Dl[i][mm];
                t[i] = ((a0 + a1) + (a2 + a3)) * dinv[i];
                Tl[i][tid] = t[i];
            }
        }
        __syncthreads();

        // syrk: lower tile pairs (a>=b) distributed over 8 waves; 8x8 regs/lane
        if (K > 0) {
            int ly = lane6 >> 3, lx = lane6 & 7;
            int npair = K * (K + 1) / 2;
            for (int tix = wave; tix < npair; tix += 8) {
                int a = 0, b = 0;
                { int q = tix;
                  for (int r0 = 0; r0 < 7; ++r0) { if (q <= r0) { a = r0; b = q; break; } q -= (r0 + 1); } }
                float acc[8][8];
                #pragma unroll
                for (int r = 0; r < 8; ++r)
                    #pragma unroll
                    for (int s = 0; s < 8; ++s) acc[r][s] = 0.f;
                #pragma unroll 4
                for (int k = 0; k < 64; ++k) {
                    float av[8], bv2[8];
                    *(float4*)&av[0]  = *(const float4*)&Tl[k][a * 64 + ly * 8];
                    *(float4*)&av[4]  = *(const float4*)&Tl[k][a * 64 + ly * 8 + 4];
                    *(float4*)&bv2[0] = *(const float4*)&Tl[k][b * 64 + lx * 8];
                    *(float4*)&bv2[4] = *(const float4*)&Tl[k][b * 64 + lx * 8 + 4];
                    #pragma unroll
                    for (int r = 0; r < 8; ++r)
                        #pragma unroll
                        for (int s = 0; s < 8; ++s)
                            acc[r][s] += av[r] * bv2[s];
                }
                #pragma unroll
                for (int r = 0; r < 8; ++r) {
                    size_t off = (size_t)(col1 + a * 64 + ly * 8 + r) * DIM + col1 + b * 64 + lx * 8;
                    float4 c0 = *(float4*)&Am[off];
                    float4 c1 = *(float4*)&Am[off + 4];
                    c0.x -= acc[r][0]; c0.y -= acc[r][1]; c0.z -= acc[r][2]; c0.w -= acc[r][3];
                    c1.x -= acc[r][4]; c1.y -= acc[r][5]; c1.z -= acc[r][6]; c1.w -= acc[r][7];
                    *(float4*)&Am[off]     = c0;
                    *(float4*)&Am[off + 4] = c1;
                }
            }
        }
        __syncthreads();
    }
}

// ---------------------------------------------------------------- finalize
__global__ void k_final(const float* __restrict__ ld,
                        const int* __restrict__ counts,
                        float* __restrict__ out) {
    if (threadIdx.x == 0 && blockIdx.x == 0) {
        float disc_z  = 0.5f * ld[30];
        float disc_zb = 0.5f * ld[31];
        float comp_z = 0.f, comp_zb = 0.f, sum_ldz = 0.f, sum_ldzb = 0.f, item = 0.f;
        for (int c = 0; c < NCLS; ++c) {
            float trPi = (float)counts[c] + 1e-8f;
            float s = trPi / (2.f * (float)NROWS);
            comp_z  += s * ld[c];
            comp_zb += s * ld[10 + c];
            sum_ldz  += ld[c];
            sum_ldzb += ld[10 + c];
            item += 0.5f * ld[20 + c];
        }
        float term3 = item - 0.25f * sum_ldz - 0.25f * sum_ldzb;
        float z_total  = -(disc_z - comp_z);
        float zb_total = -(disc_zb - comp_zb);
        float errD = -((disc_z - comp_z) + (disc_zb - comp_zb) + term3);
        out[0] = errD; out[1] = z_total; out[2] = zb_total; out[3] = term3;
    }
}

// ---------------------------------------------------------------- launch
extern "C" void kernel_launch(void* const* d_in, const int* in_sizes, int n_in,
                              void* d_out, int out_size, void* d_ws, size_t ws_size,
                              hipStream_t stream) {
    (void)in_sizes; (void)n_in; (void)out_size; (void)ws_size;
    const float* Z     = (const float*)d_in[0];
    const float* Zb    = (const float*)d_in[1];
    const int*   label = (const int*)d_in[2];

    char* ws = (char*)d_ws;
    int*   counts = (int*)ws;                                    // 40 B
    float* ld     = (float*)(ws + 64);                           // 128 B
    int*   lists  = (int*)(ws + 256);                            // 320 KiB
    float* G      = (float*)(ws + 256 + (size_t)NCLS * NROWS * 4);   // 12.5 MiB
    float* A      = G + (size_t)2 * NCLS * GPAIR * 16384;        // 32 MiB
    float* out    = (float*)d_out;

    hipMemsetAsync(ws, 0, 256, stream);
    k_count<<<NROWS / 256, 256, 0, stream>>>(label, counts, lists);
    k_gram<<<dim3(GPAIR, NCLS, 2), 512, 0, stream>>>(Z, Zb, counts, lists, G);
    k_assemble<<<dim3(GPAIR, NMAT), 256, 0, stream>>>(G, counts, A);
    k_chol<<<NMAT, 512, 0, stream>>>(A, ld);
    k_final<<<1, 64, 0, stream>>>(ld, counts, out);
}

// Round 8
// 571.785 us; speedup vs baseline: 1.1811x; 1.1811x over previous
//
#include <hip/hip_runtime.h>
#include <math.h>

#define NROWS 8192
#define DIM   512
#define NCLS  10
#define GT    4        // 128-wide tile grid (4x4)
#define GPAIR 10       // lower-triangle 128-tile pairs
#define NMAT  32

typedef __attribute__((ext_vector_type(8))) short bf16x8;
typedef __attribute__((ext_vector_type(4))) float f32x4;

__device__ __forceinline__ float rdlane(float v, int l) {
    return __int_as_float(__builtin_amdgcn_readlane(__float_as_int(v), l));
}

// ---------------------------------------------------------------- counts/lists
__global__ __launch_bounds__(256) void k_count(const int* __restrict__ label,
                                               int* __restrict__ counts,
                                               int* __restrict__ lists) {
    __shared__ int hist[NCLS];
    __shared__ int base[NCLS];
    __shared__ int lofs[NCLS];
    int tid = threadIdx.x;
    int i = blockIdx.x * 256 + tid;
    if (tid < NCLS) { hist[tid] = 0; lofs[tid] = 0; }
    __syncthreads();
    int c = label[i];
    atomicAdd(&hist[c], 1);
    __syncthreads();
    if (tid < NCLS) base[tid] = atomicAdd(&counts[tid], hist[tid]);
    __syncthreads();
    int lpos = atomicAdd(&lofs[c], 1);
    lists[(size_t)c * NROWS + base[c] + lpos] = i;
}

// ---------------------------------------------------------------- per-class Grams
__global__ __launch_bounds__(512) void k_gram(const float* __restrict__ Z,
                                              const float* __restrict__ Zb,
                                              const int* __restrict__ counts,
                                              const int* __restrict__ lists,
                                              float* __restrict__ G) {
    int pt = blockIdx.x;
    int c  = blockIdx.y;
    int tz = blockIdx.z;
    int ti = 0, tj = 0;
    { int p = pt;
      for (int r = 0; r < GT; ++r) { if (p <= r) { ti = r; tj = p; break; } p -= (r + 1); } }
    bool diag = (ti == tj);

    const float* __restrict__ src = tz ? Zb : Z;
    float* __restrict__ Gout = G + (((size_t)tz * NCLS + c) * GPAIR + pt) * 16384;
    int cnt = counts[c];
    const int* __restrict__ list = lists + (size_t)c * NROWS;

    __shared__ float As[2][16][132];
    __shared__ float Bs[2][16][132];
    int tid = threadIdx.x;
    int gid = tid >> 8;
    int t   = tid & 255;
    int tx = t & 15, ty = t >> 4;
    int srow = t >> 4, sc4 = t & 15;

    float acc[8][8];
    #pragma unroll
    for (int r = 0; r < 8; ++r)
        #pragma unroll
        for (int s = 0; s < 8; ++s) acc[r][s] = 0.f;

    for (int base0 = 0; base0 < cnt; base0 += 32) {
        int gr = base0 + gid * 16 + srow;
        float4 va0 = make_float4(0.f, 0.f, 0.f, 0.f), va1 = va0, vb0 = va0, vb1 = va0;
        if (gr < cnt) {
            int ridx = list[gr];
            const float* __restrict__ rp = src + (size_t)ridx * DIM;
            va0 = *(const float4*)&rp[ti * 128 + sc4 * 4];
            va1 = *(const float4*)&rp[ti * 128 + 64 + sc4 * 4];
            if (!diag) {
                vb0 = *(const float4*)&rp[tj * 128 + sc4 * 4];
                vb1 = *(const float4*)&rp[tj * 128 + 64 + sc4 * 4];
            }
        }
        *(float4*)&As[gid][srow][sc4 * 4]      = va0;
        *(float4*)&As[gid][srow][64 + sc4 * 4] = va1;
        if (!diag) {
            *(float4*)&Bs[gid][srow][sc4 * 4]      = vb0;
            *(float4*)&Bs[gid][srow][64 + sc4 * 4] = vb1;
        }
        __syncthreads();

        const float (*__restrict__ Ap)[132] = As[gid];
        const float (*__restrict__ Bp)[132] = diag ? As[gid] : Bs[gid];
        #pragma unroll
        for (int kk = 0; kk < 16; ++kk) {
            float a[8], b[8];
            *(float4*)&a[0] = *(const float4*)&Ap[kk][ty * 4];
            *(float4*)&a[4] = *(const float4*)&Ap[kk][64 + ty * 4];
            *(float4*)&b[0] = *(const float4*)&Bp[kk][tx * 4];
            *(float4*)&b[4] = *(const float4*)&Bp[kk][64 + tx * 4];
            #pragma unroll
            for (int r = 0; r < 8; ++r)
                #pragma unroll
                for (int s = 0; s < 8; ++s)
                    acc[r][s] += a[r] * b[s];
        }
        __syncthreads();
    }

    // fully unrolled (rule #20) LDS reduction of group1 into group0
    float* red = (float*)&As[0][0][0];
    #pragma unroll
    for (int r = 0; r < 8; ++r) {
        __syncthreads();
        if (gid == 1) {
            #pragma unroll
            for (int s = 0; s < 8; ++s) red[t * 8 + s] = acc[r][s];
        }
        __syncthreads();
        if (gid == 0) {
            #pragma unroll
            for (int s = 0; s < 8; ++s) acc[r][s] += red[t * 8 + s];
        }
    }
    if (gid == 0) {
        #pragma unroll
        for (int r = 0; r < 8; ++r) {
            int row = (r < 4) ? (ty * 4 + r) : (64 + ty * 4 + r - 4);
            float4 v0 = make_float4(acc[r][0], acc[r][1], acc[r][2], acc[r][3]);
            float4 v1 = make_float4(acc[r][4], acc[r][5], acc[r][6], acc[r][7]);
            *(float4*)&Gout[(size_t)row * 128 + tx * 4]      = v0;
            *(float4*)&Gout[(size_t)row * 128 + 64 + tx * 4] = v1;
        }
    }
}

// ---------------------------------------------------------------- assemble (lower tiles only)
__global__ __launch_bounds__(256) void k_assemble(const float* __restrict__ G,
                                                  const int* __restrict__ counts,
                                                  float* __restrict__ A) {
    int pt = blockIdx.x;
    int m  = blockIdx.y;
    int ti = 0, tj = 0;
    { int p = pt;
      for (int r = 0; r < GT; ++r) { if (p <= r) { ti = r; tj = p; break; } p -= (r + 1); } }

    const size_t TILE = 16384;
    const float* __restrict__ Gz  = G;
    const float* __restrict__ Gzb = G + (size_t)NCLS * GPAIR * TILE;
    float* __restrict__ Am = A + (size_t)m * DIM * DIM;
    int tid = threadIdx.x;

    int mode; int c; float sc;
    if (m < 10)      { mode = 0; c = m;      sc = 1024.f / ((float)counts[c] + 1e-8f); }
    else if (m < 20) { mode = 1; c = m - 10; sc = 1024.f / ((float)counts[c] + 1e-8f); }
    else if (m < 30) { mode = 2; c = m - 20; sc = 512.f / (float)counts[c]; }
    else             { mode = (m == 30) ? 3 : 4; c = 0; sc = 0.125f; }

    #pragma unroll 1
    for (int h = 0; h < 16; ++h) {
        int id = h * 256 + tid;
        int row = id >> 5, c4 = id & 31;
        size_t off = (size_t)row * 128 + c4 * 4;
        float4 g = make_float4(0.f, 0.f, 0.f, 0.f);
        if (mode == 0) {
            g = *(const float4*)&Gz[((size_t)c * GPAIR + pt) * TILE + off];
        } else if (mode == 1) {
            g = *(const float4*)&Gzb[((size_t)c * GPAIR + pt) * TILE + off];
        } else if (mode == 2) {
            float4 a = *(const float4*)&Gz [((size_t)c * GPAIR + pt) * TILE + off];
            float4 b = *(const float4*)&Gzb[((size_t)c * GPAIR + pt) * TILE + off];
            g.x = a.x + b.x; g.y = a.y + b.y; g.z = a.z + b.z; g.w = a.w + b.w;
        } else if (mode == 3) {
            for (int cc = 0; cc < NCLS; ++cc) {
                float4 t = *(const float4*)&Gz[((size_t)cc * GPAIR + pt) * TILE + off];
                g.x += t.x; g.y += t.y; g.z += t.z; g.w += t.w;
            }
        } else {
            for (int cc = 0; cc < NCLS; ++cc) {
                float4 t = *(const float4*)&Gzb[((size_t)cc * GPAIR + pt) * TILE + off];
                g.x += t.x; g.y += t.y; g.z += t.z; g.w += t.w;
            }
        }
        g.x *= sc; g.y *= sc; g.z *= sc; g.w *= sc;
        if (ti == tj) {
            int cb = c4 * 4;
            if (row == cb)     g.x += 1.f;
            if (row == cb + 1) g.y += 1.f;
            if (row == cb + 2) g.z += 1.f;
            if (row == cb + 3) g.w += 1.f;
        }
        *(float4*)&Am[(size_t)(ti * 128 + row) * DIM + tj * 128 + c4 * 4] = g;
    }
}

// ---------------------------------------------------------------- full Cholesky, ONE launch
// Per panel: fact (wave0, readlane) || trsm (waves 1..K, L in registers, readlane
// broadcasts — zero LDS reads in the solve) -> T as bf16 hi/lo in swizzled LDS
// -> syrk via MFMA 16x16x32 bf16, 3-product hi/lo split (rel err ~2^-16).
__global__ __launch_bounds__(512) void k_chol(float* __restrict__ A,
                                              float* __restrict__ ld) {
    int m = blockIdx.x;
    float* __restrict__ Am = A + (size_t)m * DIM * DIM;
    int tid = threadIdx.x;
    int wave = tid >> 6, lane = tid & 63;

    __shared__ float  Dl[64][68];       // 17.0 KB
    __shared__ float  dinv[64];
    __shared__ ushort Thi[448][64];     // 56 KB, XOR-swizzled: idx ^= (row&7)<<3
    __shared__ ushort Tlo[448][64];     // 56 KB

    #pragma unroll 1
    for (int p = 0; p < 8; ++p) {
        int col0 = p * 64, col1 = col0 + 64;
        int mt = DIM - col1;
        int K = mt >> 6;
        int chunk = wave - 1;
        bool is_trsm = (chunk >= 0 && chunk < K);

        // stage diag tile
        for (int h = tid; h < 1024; h += 512) {
            int r = h >> 4, c4 = h & 15;
            *(float4*)&Dl[r][c4 * 4] = *(const float4*)&Am[(size_t)(col0 + r) * DIM + col0 + c4 * 4];
        }
        __syncthreads();

        // fact by wave 0 (readlane broadcasts)
        if (wave == 0) {
            float row_[64];
            #pragma unroll
            for (int j = 0; j < 64; ++j) row_[j] = Dl[lane][j];
            float dval = 1.f;
            #pragma unroll
            for (int k = 0; k < 64; ++k) {
                float piv = rdlane(row_[k], k);
                float s = 1.0f / sqrtf(piv);
                float lik = row_[k] * s;
                dval = (lane == k) ? lik : dval;
                row_[k] = lik;
                #pragma unroll
                for (int j = k + 1; j < 64; ++j)
                    row_[j] -= lik * rdlane(lik, j);
            }
            #pragma unroll
            for (int j = 0; j < 64; ++j) Dl[lane][j] = row_[j];
            dinv[lane] = 1.f / dval;
            float v = 2.f * logf(dval);
            #pragma unroll
            for (int off = 32; off > 0; off >>= 1) v += __shfl_down(v, off);
            if (lane == 0) atomicAdd(&ld[m], v);
        }
        __syncthreads();

        // trsm: wave (1+c) solves chunk c; L row-per-lane in registers
        if (is_trsm) {
            float Lreg[64];
            #pragma unroll
            for (int j4 = 0; j4 < 16; ++j4)
                *(float4*)&Lreg[j4 * 4] = *(const float4*)&Dl[lane][j4 * 4];
            float dv = dinv[lane];
            const float* __restrict__ Brow = Am + (size_t)(col1 + chunk * 64 + lane) * DIM + col0;
            float t[64];
            float4 bv;
            #pragma unroll
            for (int i = 0; i < 64; ++i) {
                if ((i & 3) == 0) bv = *(const float4*)&Brow[i];
                float a0 = (i & 3) == 0 ? bv.x : ((i & 3) == 1 ? bv.y : ((i & 3) == 2 ? bv.z : bv.w));
                float a1 = 0.f, a2 = 0.f, a3 = 0.f;
                int mm = 0;
                #pragma unroll
                for (; mm + 3 < i; mm += 4) {
                    a0 -= t[mm]     * rdlane(Lreg[mm],     i);
                    a1 -= t[mm + 1] * rdlane(Lreg[mm + 1], i);
                    a2 -= t[mm + 2] * rdlane(Lreg[mm + 2], i);
                    a3 -= t[mm + 3] * rdlane(Lreg[mm + 3], i);
                }
                #pragma unroll
                for (; mm < i; ++mm) a0 -= t[mm] * rdlane(Lreg[mm], i);
                t[i] = ((a0 + a1) + (a2 + a3)) * rdlane(dv, i);
            }
            // convert to bf16 hi/lo, swizzled store (pairs -> b32)
            int row = chunk * 64 + lane;
            int hsw = (row & 7) << 3;
            #pragma unroll
            for (int i = 0; i < 64; i += 2) {
                uint u0 = __float_as_uint(t[i]);
                float h0f = __uint_as_float(u0 & 0xFFFF0000u);
                uint l0 = __float_as_uint(t[i] - h0f);
                uint u1 = __float_as_uint(t[i + 1]);
                float h1f = __uint_as_float(u1 & 0xFFFF0000u);
                uint l1 = __float_as_uint(t[i + 1] - h1f);
                int idx = i ^ hsw;
                *(uint*)&Thi[row][idx] = (u0 >> 16) | (u1 & 0xFFFF0000u);
                *(uint*)&Tlo[row][idx] = (l0 >> 16) | (l1 & 0xFFFF0000u);
            }
        }
        __syncthreads();

        // syrk via MFMA: pairs (a>=b) over 8 waves
        if (K > 0) {
            int lr = lane & 15, kb = lane >> 4;
            int npair = K * (K + 1) / 2;
            for (int tix = wave; tix < npair; tix += 8) {
                int a = 0, b = 0;
                { int q = tix;
                  for (int r0 = 0; r0 < 7; ++r0) { if (q <= r0) { a = r0; b = q; break; } q -= (r0 + 1); } }
                f32x4 acc[4][4];
                #pragma unroll
                for (int it = 0; it < 4; ++it)
                    #pragma unroll
                    for (int jt = 0; jt < 4; ++jt)
                        acc[it][jt] = (f32x4){0.f, 0.f, 0.f, 0.f};
                #pragma unroll
                for (int k0 = 0; k0 < 64; k0 += 32) {
                    bf16x8 Ah[4], Al[4], Bh[4], Bl[4];
                    int idx = (k0 + kb * 8) ^ ((lr & 7) << 3);   // rows below are 8-aligned + lr
                    #pragma unroll
                    for (int it = 0; it < 4; ++it) {
                        int rowA = a * 64 + it * 16 + lr;
                        Ah[it] = *(const bf16x8*)&Thi[rowA][idx];
                        Al[it] = *(const bf16x8*)&Tlo[rowA][idx];
                        int rowB = b * 64 + it * 16 + lr;
                        Bh[it] = *(const bf16x8*)&Thi[rowB][idx];
                        Bl[it] = *(const bf16x8*)&Tlo[rowB][idx];
                    }
                    #pragma unroll
                    for (int it = 0; it < 4; ++it)
                        #pragma unroll
                        for (int jt = 0; jt < 4; ++jt) {
                            acc[it][jt] = __builtin_amdgcn_mfma_f32_16x16x32_bf16(Ah[it], Bh[jt], acc[it][jt], 0, 0, 0);
                            acc[it][jt] = __builtin_amdgcn_mfma_f32_16x16x32_bf16(Ah[it], Bl[jt], acc[it][jt], 0, 0, 0);
                            acc[it][jt] = __builtin_amdgcn_mfma_f32_16x16x32_bf16(Al[it], Bh[jt], acc[it][jt], 0, 0, 0);
                        }
                }
                // C/D layout (m89-verified): col = lane&15, row = (lane>>4)*4 + reg
                #pragma unroll
                for (int it = 0; it < 4; ++it)
                    #pragma unroll
                    for (int jt = 0; jt < 4; ++jt)
                        #pragma unroll
                        for (int rg = 0; rg < 4; ++rg) {
                            int gi = col1 + a * 64 + it * 16 + kb * 4 + rg;
                            int gj = col1 + b * 64 + jt * 16 + lr;
                            Am[(size_t)gi * DIM + gj] -= acc[it][jt][rg];
                        }
            }
        }
        __syncthreads();
    }
}

// ---------------------------------------------------------------- finalize
__global__ void k_final(const float* __restrict__ ld,
                        const int* __restrict__ counts,
                        float* __restrict__ out) {
    if (threadIdx.x == 0 && blockIdx.x == 0) {
        float disc_z  = 0.5f * ld[30];
        float disc_zb = 0.5f * ld[31];
        float comp_z = 0.f, comp_zb = 0.f, sum_ldz = 0.f, sum_ldzb = 0.f, item = 0.f;
        for (int c = 0; c < NCLS; ++c) {
            float trPi = (float)counts[c] + 1e-8f;
            float s = trPi / (2.f * (float)NROWS);
            comp_z  += s * ld[c];
            comp_zb += s * ld[10 + c];
            sum_ldz  += ld[c];
            sum_ldzb += ld[10 + c];
            item += 0.5f * ld[20 + c];
        }
        float term3 = item - 0.25f * sum_ldz - 0.25f * sum_ldzb;
        float z_total  = -(disc_z - comp_z);
        float zb_total = -(disc_zb - comp_zb);
        float errD = -((disc_z - comp_z) + (disc_zb - comp_zb) + term3);
        out[0] = errD; out[1] = z_total; out[2] = zb_total; out[3] = term3;
    }
}

// ---------------------------------------------------------------- launch
extern "C" void kernel_launch(void* const* d_in, const int* in_sizes, int n_in,
                              void* d_out, int out_size, void* d_ws, size_t ws_size,
                              hipStream_t stream) {
    (void)in_sizes; (void)n_in; (void)out_size; (void)ws_size;
    const float* Z     = (const float*)d_in[0];
    const float* Zb    = (const float*)d_in[1];
    const int*   label = (const int*)d_in[2];

    char* ws = (char*)d_ws;
    int*   counts = (int*)ws;
    float* ld     = (float*)(ws + 64);
    int*   lists  = (int*)(ws + 256);
    float* G      = (float*)(ws + 256 + (size_t)NCLS * NROWS * 4);
    float* A      = G + (size_t)2 * NCLS * GPAIR * 16384;
    float* out    = (float*)d_out;

    hipMemsetAsync(ws, 0, 256, stream);
    k_count<<<NROWS / 256, 256, 0, stream>>>(label, counts, lists);
    k_gram<<<dim3(GPAIR, NCLS, 2), 512, 0, stream>>>(Z, Zb, counts, lists, G);
    k_assemble<<<dim3(GPAIR, NMAT), 256, 0, stream>>>(G, counts, A);
    k_chol<<<NMAT, 512, 0, stream>>>(A, ld);
    k_final<<<1, 64, 0, stream>>>(ld, counts, out);
}

// Round 10
// 509.027 us; speedup vs baseline: 1.3268x; 1.1233x over previous
//
#include <hip/hip_runtime.h>
#include <math.h>

#define NROWS 8192
#define DIM   512
#define NCLS  10
#define GT    4        // 128-wide tile grid (4x4)
#define GPAIR 10       // lower-triangle 128-tile pairs
#define NMAT  32

typedef __attribute__((ext_vector_type(8))) short bf16x8;
typedef __attribute__((ext_vector_type(4))) float f32x4;

__device__ __forceinline__ float rdlane(float v, int l) {
    return __int_as_float(__builtin_amdgcn_readlane(__float_as_int(v), l));
}

// fact 64x64 lower Cholesky by one wave: row-per-lane, readlane broadcasts.
// Consumes/produces Dl (only lower triangle meaningful), writes dinv, adds logdet.
__device__ __forceinline__ void fact64(float (*Dl)[68], float* dinv, float* ldm, int lane) {
    float row_[64];
    #pragma unroll
    for (int j = 0; j < 64; ++j) row_[j] = Dl[lane][j];
    float dval = 1.f;
    #pragma unroll
    for (int k = 0; k < 64; ++k) {
        float piv = rdlane(row_[k], k);
        float s = 1.0f / sqrtf(piv);
        float lik = row_[k] * s;
        dval = (lane == k) ? lik : dval;
        row_[k] = lik;
        #pragma unroll
        for (int j = k + 1; j < 64; ++j)
            row_[j] -= lik * rdlane(lik, j);
    }
    #pragma unroll
    for (int j = 0; j < 64; ++j) Dl[lane][j] = row_[j];
    dinv[lane] = 1.f / dval;
    float v = 2.f * logf(dval);
    #pragma unroll
    for (int off = 32; off > 0; off >>= 1) v += __shfl_down(v, off);
    if (lane == 0) atomicAdd(ldm, v);
}

// ---------------------------------------------------------------- counts/lists
__global__ __launch_bounds__(256) void k_count(const int* __restrict__ label,
                                               int* __restrict__ counts,
                                               int* __restrict__ lists) {
    __shared__ int hist[NCLS];
    __shared__ int base[NCLS];
    __shared__ int lofs[NCLS];
    int tid = threadIdx.x;
    int i = blockIdx.x * 256 + tid;
    if (tid < NCLS) { hist[tid] = 0; lofs[tid] = 0; }
    __syncthreads();
    int c = label[i];
    atomicAdd(&hist[c], 1);
    __syncthreads();
    if (tid < NCLS) base[tid] = atomicAdd(&counts[tid], hist[tid]);
    __syncthreads();
    int lpos = atomicAdd(&lofs[c], 1);
    lists[(size_t)c * NROWS + base[c] + lpos] = i;
}

// ---------------------------------------------------------------- per-class Grams
// 64-deep k-chunks per barrier (2 groups x 32 rows) + register prefetch.
__global__ __launch_bounds__(512) void k_gram(const float* __restrict__ Z,
                                              const float* __restrict__ Zb,
                                              const int* __restrict__ counts,
                                              const int* __restrict__ lists,
                                              float* __restrict__ G) {
    int pt = blockIdx.x;
    int c  = blockIdx.y;
    int tz = blockIdx.z;
    int ti = 0, tj = 0;
    { int p = pt;
      for (int r = 0; r < GT; ++r) { if (p <= r) { ti = r; tj = p; break; } p -= (r + 1); } }
    bool diag = (ti == tj);

    const float* __restrict__ src = tz ? Zb : Z;
    float* __restrict__ Gout = G + (((size_t)tz * NCLS + c) * GPAIR + pt) * 16384;
    int cnt = counts[c];
    const int* __restrict__ list = lists + (size_t)c * NROWS;

    __shared__ float As[2][32][132];
    __shared__ float Bs[2][32][132];
    int tid = threadIdx.x;
    int gid = tid >> 8;
    int t   = tid & 255;
    int tx = t & 15, ty = t >> 4;
    int sr = t >> 3, se = t & 7;        // staging: row 0..31, 16-col eighth

    float acc[8][8];
    #pragma unroll
    for (int r = 0; r < 8; ++r)
        #pragma unroll
        for (int s = 0; s < 8; ++s) acc[r][s] = 0.f;

    float4 pa[4], pb[4];
    // prefetch chunk 0
    {
        int gr = gid * 32 + sr;
        #pragma unroll
        for (int q = 0; q < 4; ++q) { pa[q] = make_float4(0.f,0.f,0.f,0.f); pb[q] = pa[q]; }
        if (gr < cnt) {
            const float* __restrict__ rp = src + (size_t)list[gr] * DIM;
            #pragma unroll
            for (int q = 0; q < 4; ++q) {
                pa[q] = *(const float4*)&rp[ti * 128 + se * 16 + q * 4];
                if (!diag) pb[q] = *(const float4*)&rp[tj * 128 + se * 16 + q * 4];
            }
        }
    }

    for (int base0 = 0; base0 < cnt; base0 += 64) {
        // commit prefetched chunk to LDS
        #pragma unroll
        for (int q = 0; q < 4; ++q) {
            *(float4*)&As[gid][sr][se * 16 + q * 4] = pa[q];
            if (!diag) *(float4*)&Bs[gid][sr][se * 16 + q * 4] = pb[q];
        }
        __syncthreads();
        // prefetch next chunk (overlaps compute)
        {
            int gr = base0 + 64 + gid * 32 + sr;
            #pragma unroll
            for (int q = 0; q < 4; ++q) { pa[q] = make_float4(0.f,0.f,0.f,0.f); pb[q] = pa[q]; }
            if (gr < cnt) {
                const float* __restrict__ rp = src + (size_t)list[gr] * DIM;
                #pragma unroll
                for (int q = 0; q < 4; ++q) {
                    pa[q] = *(const float4*)&rp[ti * 128 + se * 16 + q * 4];
                    if (!diag) pb[q] = *(const float4*)&rp[tj * 128 + se * 16 + q * 4];
                }
            }
        }
        const float (*__restrict__ Ap)[132] = As[gid];
        const float (*__restrict__ Bp)[132] = diag ? As[gid] : Bs[gid];
        #pragma unroll
        for (int kk = 0; kk < 32; ++kk) {
            float a[8], b[8];
            *(float4*)&a[0] = *(const float4*)&Ap[kk][ty * 4];
            *(float4*)&a[4] = *(const float4*)&Ap[kk][64 + ty * 4];
            *(float4*)&b[0] = *(const float4*)&Bp[kk][tx * 4];
            *(float4*)&b[4] = *(const float4*)&Bp[kk][64 + tx * 4];
            #pragma unroll
            for (int r = 0; r < 8; ++r)
                #pragma unroll
                for (int s = 0; s < 8; ++s)
                    acc[r][s] += a[r] * b[s];
        }
        __syncthreads();
    }

    // fully unrolled (rule #20) LDS reduction of group1 into group0
    float* red = (float*)&As[0][0][0];
    #pragma unroll
    for (int r = 0; r < 8; ++r) {
        __syncthreads();
        if (gid == 1) {
            #pragma unroll
            for (int s = 0; s < 8; ++s) red[t * 8 + s] = acc[r][s];
        }
        __syncthreads();
        if (gid == 0) {
            #pragma unroll
            for (int s = 0; s < 8; ++s) acc[r][s] += red[t * 8 + s];
        }
    }
    if (gid == 0) {
        #pragma unroll
        for (int r = 0; r < 8; ++r) {
            int row = (r < 4) ? (ty * 4 + r) : (64 + ty * 4 + r - 4);
            float4 v0 = make_float4(acc[r][0], acc[r][1], acc[r][2], acc[r][3]);
            float4 v1 = make_float4(acc[r][4], acc[r][5], acc[r][6], acc[r][7]);
            *(float4*)&Gout[(size_t)row * 128 + tx * 4]      = v0;
            *(float4*)&Gout[(size_t)row * 128 + 64 + tx * 4] = v1;
        }
    }
}

// ---------------------------------------------------------------- assemble (lower tiles only)
__global__ __launch_bounds__(256) void k_assemble(const float* __restrict__ G,
                                                  const int* __restrict__ counts,
                                                  float* __restrict__ A) {
    int pt = blockIdx.x;
    int m  = blockIdx.y;
    int ti = 0, tj = 0;
    { int p = pt;
      for (int r = 0; r < GT; ++r) { if (p <= r) { ti = r; tj = p; break; } p -= (r + 1); } }

    const size_t TILE = 16384;
    const float* __restrict__ Gz  = G;
    const float* __restrict__ Gzb = G + (size_t)NCLS * GPAIR * TILE;
    float* __restrict__ Am = A + (size_t)m * DIM * DIM;
    int tid = threadIdx.x;

    int mode; int c; float sc;
    if (m < 10)      { mode = 0; c = m;      sc = 1024.f / ((float)counts[c] + 1e-8f); }
    else if (m < 20) { mode = 1; c = m - 10; sc = 1024.f / ((float)counts[c] + 1e-8f); }
    else if (m < 30) { mode = 2; c = m - 20; sc = 512.f / (float)counts[c]; }
    else             { mode = (m == 30) ? 3 : 4; c = 0; sc = 0.125f; }

    #pragma unroll 1
    for (int h = 0; h < 16; ++h) {
        int id = h * 256 + tid;
        int row = id >> 5, c4 = id & 31;
        size_t off = (size_t)row * 128 + c4 * 4;
        float4 g = make_float4(0.f, 0.f, 0.f, 0.f);
        if (mode == 0) {
            g = *(const float4*)&Gz[((size_t)c * GPAIR + pt) * TILE + off];
        } else if (mode == 1) {
            g = *(const float4*)&Gzb[((size_t)c * GPAIR + pt) * TILE + off];
        } else if (mode == 2) {
            float4 a = *(const float4*)&Gz [((size_t)c * GPAIR + pt) * TILE + off];
            float4 b = *(const float4*)&Gzb[((size_t)c * GPAIR + pt) * TILE + off];
            g.x = a.x + b.x; g.y = a.y + b.y; g.z = a.z + b.z; g.w = a.w + b.w;
        } else if (mode == 3) {
            for (int cc = 0; cc < NCLS; ++cc) {
                float4 t = *(const float4*)&Gz[((size_t)cc * GPAIR + pt) * TILE + off];
                g.x += t.x; g.y += t.y; g.z += t.z; g.w += t.w;
            }
        } else {
            for (int cc = 0; cc < NCLS; ++cc) {
                float4 t = *(const float4*)&Gzb[((size_t)cc * GPAIR + pt) * TILE + off];
                g.x += t.x; g.y += t.y; g.z += t.z; g.w += t.w;
            }
        }
        g.x *= sc; g.y *= sc; g.z *= sc; g.w *= sc;
        if (ti == tj) {
            int cb = c4 * 4;
            if (row == cb)     g.x += 1.f;
            if (row == cb + 1) g.y += 1.f;
            if (row == cb + 2) g.z += 1.f;
            if (row == cb + 3) g.w += 1.f;
        }
        *(float4*)&Am[(size_t)(ti * 128 + row) * DIM + tj * 128 + c4 * 4] = g;
    }
}

// ---------------------------------------------------------------- full Cholesky, ONE launch
// Pipelined: per panel p, phase A = trsm (waves 1..K). Phase B: wave0 computes
// trailing tile(0,0) via MFMA, keeps it OFF global (orig - acc -> Dl) and
// immediately factorizes panel p+1; waves 1..7 do all other syrk tiles (global RMW).
// 2 barriers/panel.
__global__ __launch_bounds__(512, 2) void k_chol(float* __restrict__ A,
                                                 float* __restrict__ ld) {
    int m = blockIdx.x;
    float* __restrict__ Am = A + (size_t)m * DIM * DIM;
    int tid = threadIdx.x;
    int wave = tid >> 6, lane = tid & 63;

    __shared__ float  Dl[64][68];
    __shared__ float  dinv[64];
    __shared__ ushort Thi[448][64];     // XOR-swizzled: idx ^= (row&7)<<3
    __shared__ ushort Tlo[448][64];

    // prologue: stage diag(0), fact(0)
    for (int h = tid; h < 1024; h += 512) {
        int r = h >> 4, c4 = h & 15;
        *(float4*)&Dl[r][c4 * 4] = *(const float4*)&Am[(size_t)r * DIM + c4 * 4];
    }
    __syncthreads();
    if (wave == 0) fact64(Dl, dinv, &ld[m], lane);
    __syncthreads();

    #pragma unroll 1
    for (int p = 0; p < 7; ++p) {
        int col0 = p * 64, col1 = col0 + 64;
        int mt = DIM - col1;
        int K = mt >> 6;
        int npair = K * (K + 1) / 2;

        // ---- phase A: trsm (waves 1..K), L row-per-lane regs, readlane broadcasts
        int chunk = wave - 1;
        if (chunk >= 0 && chunk < K) {
            float Lreg[64];
            #pragma unroll
            for (int j4 = 0; j4 < 16; ++j4)
                *(float4*)&Lreg[j4 * 4] = *(const float4*)&Dl[lane][j4 * 4];
            float dv = dinv[lane];
            const float* __restrict__ Brow = Am + (size_t)(col1 + chunk * 64 + lane) * DIM + col0;
            float t[64];
            float4 bv;
            #pragma unroll
            for (int i = 0; i < 64; ++i) {
                if ((i & 3) == 0) bv = *(const float4*)&Brow[i];
                float a0 = (i & 3) == 0 ? bv.x : ((i & 3) == 1 ? bv.y : ((i & 3) == 2 ? bv.z : bv.w));
                float a1 = 0.f, a2 = 0.f, a3 = 0.f;
                int mm = 0;
                #pragma unroll
                for (; mm + 3 < i; mm += 4) {
                    a0 -= t[mm]     * rdlane(Lreg[mm],     i);
                    a1 -= t[mm + 1] * rdlane(Lreg[mm + 1], i);
                    a2 -= t[mm + 2] * rdlane(Lreg[mm + 2], i);
                    a3 -= t[mm + 3] * rdlane(Lreg[mm + 3], i);
                }
                #pragma unroll
                for (; mm < i; ++mm) a0 -= t[mm] * rdlane(Lreg[mm], i);
                t[i] = ((a0 + a1) + (a2 + a3)) * rdlane(dv, i);
            }
            int row = chunk * 64 + lane;
            int hsw = (row & 7) << 3;
            #pragma unroll
            for (int i = 0; i < 64; i += 2) {
                uint u0 = __float_as_uint(t[i]);
                float h0f = __uint_as_float(u0 & 0xFFFF0000u);
                uint l0 = __float_as_uint(t[i] - h0f);
                uint u1 = __float_as_uint(t[i + 1]);
                float h1f = __uint_as_float(u1 & 0xFFFF0000u);
                uint l1 = __float_as_uint(t[i + 1] - h1f);
                int idx = i ^ hsw;
                *(uint*)&Thi[row][idx] = (u0 >> 16) | (u1 & 0xFFFF0000u);
                *(uint*)&Tlo[row][idx] = (l0 >> 16) | (l1 & 0xFFFF0000u);
            }
        }
        __syncthreads();

        // ---- phase B
        int lr = lane & 15, kb = lane >> 4;
        if (wave == 0) {
            // tile (0,0): MFMA acc, Dl = orig - acc (no global write), then fact(p+1)
            f32x4 acc[4][4];
            #pragma unroll
            for (int it = 0; it < 4; ++it)
                #pragma unroll
                for (int jt = 0; jt < 4; ++jt)
                    acc[it][jt] = (f32x4){0.f, 0.f, 0.f, 0.f};
            #pragma unroll
            for (int k0 = 0; k0 < 64; k0 += 32) {
                bf16x8 Ah[4], Al[4];
                int idx = (k0 + kb * 8) ^ ((lr & 7) << 3);
                #pragma unroll
                for (int it = 0; it < 4; ++it) {
                    int rowA = it * 16 + lr;
                    Ah[it] = *(const bf16x8*)&Thi[rowA][idx];
                    Al[it] = *(const bf16x8*)&Tlo[rowA][idx];
                }
                #pragma unroll
                for (int it = 0; it < 4; ++it)
                    #pragma unroll
                    for (int jt = 0; jt < 4; ++jt) {
                        acc[it][jt] = __builtin_amdgcn_mfma_f32_16x16x32_bf16(Ah[it], Ah[jt], acc[it][jt], 0, 0, 0);
                        acc[it][jt] = __builtin_amdgcn_mfma_f32_16x16x32_bf16(Ah[it], Al[jt], acc[it][jt], 0, 0, 0);
                        acc[it][jt] = __builtin_amdgcn_mfma_f32_16x16x32_bf16(Al[it], Ah[jt], acc[it][jt], 0, 0, 0);
                    }
            }
            #pragma unroll
            for (int it = 0; it < 4; ++it)
                #pragma unroll
                for (int jt = 0; jt < 4; ++jt)
                    #pragma unroll
                    for (int rg = 0; rg < 4; ++rg) {
                        int r = it * 16 + kb * 4 + rg;
                        int cg = jt * 16 + lr;
                        float orig = Am[(size_t)(col1 + r) * DIM + col1 + cg];
                        Dl[r][cg] = orig - acc[it][jt][rg];
                    }
            fact64(Dl, dinv, &ld[m], lane);
        } else {
            // all other syrk tiles (tix >= 1), global RMW
            for (int tix = wave; tix < npair; tix += 7) {
                int a = 0, b = 0;
                { int q = tix;
                  for (int r0 = 0; r0 < 7; ++r0) { if (q <= r0) { a = r0; b = q; break; } q -= (r0 + 1); } }
                f32x4 acc[4][4];
                #pragma unroll
                for (int it = 0; it < 4; ++it)
                    #pragma unroll
                    for (int jt = 0; jt < 4; ++jt)
                        acc[it][jt] = (f32x4){0.f, 0.f, 0.f, 0.f};
                #pragma unroll
                for (int k0 = 0; k0 < 64; k0 += 32) {
                    bf16x8 Ah[4], Al[4], Bh[4], Bl[4];
                    int idx = (k0 + kb * 8) ^ ((lr & 7) << 3);
                    #pragma unroll
                    for (int it = 0; it < 4; ++it) {
                        int rowA = a * 64 + it * 16 + lr;
                        Ah[it] = *(const bf16x8*)&Thi[rowA][idx];
                        Al[it] = *(const bf16x8*)&Tlo[rowA][idx];
                        int rowB = b * 64 + it * 16 + lr;
                        Bh[it] = *(const bf16x8*)&Thi[rowB][idx];
                        Bl[it] = *(const bf16x8*)&Tlo[rowB][idx];
                    }
                    #pragma unroll
                    for (int it = 0; it < 4; ++it)
                        #pragma unroll
                        for (int jt = 0; jt < 4; ++jt) {
                            acc[it][jt] = __builtin_amdgcn_mfma_f32_16x16x32_bf16(Ah[it], Bh[jt], acc[it][jt], 0, 0, 0);
                            acc[it][jt] = __builtin_amdgcn_mfma_f32_16x16x32_bf16(Ah[it], Bl[jt], acc[it][jt], 0, 0, 0);
                            acc[it][jt] = __builtin_amdgcn_mfma_f32_16x16x32_bf16(Al[it], Bh[jt], acc[it][jt], 0, 0, 0);
                        }
                }
                #pragma unroll
                for (int it = 0; it < 4; ++it)
                    #pragma unroll
                    for (int jt = 0; jt < 4; ++jt)
                        #pragma unroll
                        for (int rg = 0; rg < 4; ++rg) {
                            int gi = col1 + a * 64 + it * 16 + kb * 4 + rg;
                            int gj = col1 + b * 64 + jt * 16 + lr;
                            Am[(size_t)gi * DIM + gj] -= acc[it][jt][rg];
                        }
            }
        }
        __syncthreads();
    }
}

// ---------------------------------------------------------------- finalize
__global__ void k_final(const float* __restrict__ ld,
                        const int* __restrict__ counts,
                        float* __restrict__ out) {
    if (threadIdx.x == 0 && blockIdx.x == 0) {
        float disc_z  = 0.5f * ld[30];
        float disc_zb = 0.5f * ld[31];
        float comp_z = 0.f, comp_zb = 0.f, sum_ldz = 0.f, sum_ldzb = 0.f, item = 0.f;
        for (int c = 0; c < NCLS; ++c) {
            float trPi = (float)counts[c] + 1e-8f;
            float s = trPi / (2.f * (float)NROWS);
            comp_z  += s * ld[c];
            comp_zb += s * ld[10 + c];
            sum_ldz  += ld[c];
            sum_ldzb += ld[10 + c];
            item += 0.5f * ld[20 + c];
        }
        float term3 = item - 0.25f * sum_ldz - 0.25f * sum_ldzb;
        float z_total  = -(disc_z - comp_z);
        float zb_total = -(disc_zb - comp_zb);
        float errD = -((disc_z - comp_z) + (disc_zb - comp_zb) + term3);
        out[0] = errD; out[1] = z_total; out[2] = zb_total; out[3] = term3;
    }
}

// ---------------------------------------------------------------- launch
extern "C" void kernel_launch(void* const* d_in, const int* in_sizes, int n_in,
                              void* d_out, int out_size, void* d_ws, size_t ws_size,
                              hipStream_t stream) {
    (void)in_sizes; (void)n_in; (void)out_size; (void)ws_size;
    const float* Z     = (const float*)d_in[0];
    const float* Zb    = (const float*)d_in[1];
    const int*   label = (const int*)d_in[2];

    char* ws = (char*)d_ws;
    int*   counts = (int*)ws;
    float* ld     = (float*)(ws + 64);
    int*   lists  = (int*)(ws + 256);
    float* G      = (float*)(ws + 256 + (size_t)NCLS * NROWS * 4);
    float* A      = G + (size_t)2 * NCLS * GPAIR * 16384;
    float* out    = (float*)d_out;

    hipMemsetAsync(ws, 0, 256, stream);
    k_count<<<NROWS / 256, 256, 0, stream>>>(label, counts, lists);
    k_gram<<<dim3(GPAIR, NCLS, 2), 512, 0, stream>>>(Z, Zb, counts, lists, G);
    k_assemble<<<dim3(GPAIR, NMAT), 256, 0, stream>>>(G, counts, A);
    k_chol<<<NMAT, 512, 0, stream>>>(A, ld);
    k_final<<<1, 64, 0, stream>>>(ld, counts, out);
}